// Round 2
// baseline (788.146 us; speedup 1.0000x reference)
//
#include <hip/hip_runtime.h>
#include <hip/hip_cooperative_groups.h>
#include <math.h>

namespace cg = cooperative_groups;

#define B_DIM 512
#define C_DIM 8
#define L_DIM 16384
#define TOTAL_F4 (B_DIM * C_DIM * L_DIM / 4)   // 16,777,216 float4s
#define MAXG 1024
#define INV_N (1.0f / (float)(B_DIM * C_DIM * L_DIM))

// ws layout (floats): [0, MAXG) partials ; [4096, 4096 + 1024*44) gram
#define WS_GRAM_OFF 4096

__device__ __forceinline__ float wave_block_reduce(float v, float* lds, int tid) {
  // 64-lane shuffle reduce, then 4-wave LDS reduce; result valid in ALL threads.
#pragma unroll
  for (int off = 32; off; off >>= 1) v += __shfl_down(v, off, 64);
  const int lane = tid & 63, wv = tid >> 6;
  if (lane == 0) lds[wv] = v;
  __syncthreads();
  float r = (lds[0] + lds[1]) + (lds[2] + lds[3]);
  __syncthreads();
  return r;
}

__global__ __launch_bounds__(256, 4) void k_fused(
    const float4* __restrict__ in4, const float* __restrict__ target,
    const float* __restrict__ bias, const float* __restrict__ w_fc,
    const float* __restrict__ b_fc, float* __restrict__ out,
    float* __restrict__ partials, float* __restrict__ gram, int G) {
  cg::grid_group grid = cg::this_grid();
  const int tid = threadIdx.x, bid = blockIdx.x;
  const int lane = tid & 63, wv = tid >> 6;
  __shared__ float lds[256];

  const float* in = (const float*)in4;

  // ---------------- Phase A: global sum (4-deep unrolled grid-stride) -------
  {
    const int stride = G * 256;
    float a0 = 0.f, a1 = 0.f, a2 = 0.f, a3 = 0.f;
    int i = bid * 256 + tid;
    for (; i + 3 * stride < TOTAL_F4; i += 4 * stride) {
      float4 v0 = in4[i];
      float4 v1 = in4[i + stride];
      float4 v2 = in4[i + 2 * stride];
      float4 v3 = in4[i + 3 * stride];
      a0 += (v0.x + v0.y) + (v0.z + v0.w);
      a1 += (v1.x + v1.y) + (v1.z + v1.w);
      a2 += (v2.x + v2.y) + (v2.z + v2.w);
      a3 += (v3.x + v3.y) + (v3.z + v3.w);
    }
    for (; i < TOTAL_F4; i += stride) {
      float4 v = in4[i];
      a0 += (v.x + v.y) + (v.z + v.w);
    }
    float blk = wave_block_reduce((a0 + a1) + (a2 + a3), lds, tid);
    if (tid == 0) partials[bid] = blk;
  }

  grid.sync();

  // ---------------- Phase B: mean (redundant per block), then gram ----------
  float mu;
  {
    float m = 0.f;
    for (int k = tid; k < G; k += 256) m += partials[k];
    float tot = wave_block_reduce(m, lds, tid);
    mu = tot * INV_N;
  }
  float bias_l[C_DIM];
#pragma unroll
  for (int c = 0; c < C_DIM; ++c) bias_l[c] = bias[c];

  for (int u = bid; u < B_DIM * 2; u += G) {
    const int b = u >> 1, half = u & 1;
    const float* base = in + (size_t)b * (C_DIM * L_DIM) + half * (L_DIM / 2);

    float acc[44];
#pragma unroll
    for (int k = 0; k < 44; ++k) acc[k] = 0.f;

#pragma unroll
    for (int it = 0; it < 8; ++it) {
      const int l4 = (it * 256 + tid) * 4;  // within half (0..8191 floats)
      float4 v[C_DIM];
#pragma unroll
      for (int c = 0; c < C_DIM; ++c)
        v[c] = *reinterpret_cast<const float4*>(base + c * L_DIM + l4);
#pragma unroll
      for (int e = 0; e < 4; ++e) {
        float s[C_DIM];
#pragma unroll
        for (int c = 0; c < C_DIM; ++c) {
          float a = (e == 0) ? v[c].x : (e == 1) ? v[c].y : (e == 2) ? v[c].z : v[c].w;
          float arg = fmaf(500.f, a - mu, bias_l[c]);
          float ex = __expf(-arg);
          s[c] = __builtin_amdgcn_rcpf(1.f + ex);   // fast sigmoid, ~1ulp rcp
          acc[c] += s[c];
        }
#pragma unroll
        for (int i = 0; i < C_DIM; ++i)
#pragma unroll
          for (int j = 0; j <= i; ++j)
            acc[8 + (i * (i + 1)) / 2 + j] =
                fmaf(s[i], s[j], acc[8 + (i * (i + 1)) / 2 + j]);
      }
    }

    // block-reduce 44 accumulators
#pragma unroll
    for (int k = 0; k < 44; ++k) {
      float a = acc[k];
#pragma unroll
      for (int off = 32; off; off >>= 1) a += __shfl_down(a, off, 64);
      if (lane == 0) lds[wv * 44 + k] = a;
    }
    __syncthreads();
    if (tid < 44) {
      float r = (lds[0 * 44 + tid] + lds[1 * 44 + tid]) +
                (lds[2 * 44 + tid] + lds[3 * 44 + tid]);
      gram[u * 44 + tid] = r;
    }
    __syncthreads();
  }

  grid.sync();

  // ---------------- Phase C: block 0 — IoU, |.|, BatchNorm, Linear ----------
  if (bid != 0) return;

  float st_t[2];
#pragma unroll
  for (int h = 0; h < 2; ++h) {
    const int b = tid + h * 256;
    float S[C_DIM], T[36];
#pragma unroll
    for (int k = 0; k < C_DIM; ++k)
      S[k] = gram[b * 88 + k] + gram[b * 88 + 44 + k];
#pragma unroll
    for (int k = 0; k < 36; ++k)
      T[k] = gram[b * 88 + 8 + k] + gram[b * 88 + 44 + 8 + k];
    float st = 0.f;
#pragma unroll
    for (int i = 0; i < C_DIM; ++i)
#pragma unroll
      for (int j = 0; j <= i; ++j) {
        float inter = T[(i * (i + 1)) / 2 + j];
        float uni = (S[i] + S[j]) - inter;
        float sim = inter / uni;
        float tm = 100.f * target[b * 64 + i * 8 + j];
        st += fabsf(sim - tm);
      }
    st_t[h] = st;
  }

  __syncthreads();
  lds[tid] = st_t[0] + st_t[1];
  __syncthreads();
  for (int off = 128; off; off >>= 1) {
    if (tid < off) lds[tid] += lds[tid + off];
    __syncthreads();
  }
  const float mean = lds[0] * (1.f / 512.f);
  __syncthreads();
  float d0 = st_t[0] - mean, d1 = st_t[1] - mean;
  lds[tid] = d0 * d0 + d1 * d1;
  __syncthreads();
  for (int off = 128; off; off >>= 1) {
    if (tid < off) lds[tid] += lds[tid + off];
    __syncthreads();
  }
  const float var = lds[0] * (1.f / 512.f);
  const float inv_std = rsqrtf(var + 1e-5f);
#pragma unroll
  for (int h = 0; h < 2; ++h) {
    const int b = tid + h * 256;
    const float stn = (st_t[h] - mean) * inv_std;
#pragma unroll
    for (int k = 0; k < 3; ++k)
      out[b * 3 + k] = fmaf(stn, w_fc[k], b_fc[k]);
  }
}

extern "C" void kernel_launch(void* const* d_in, const int* in_sizes, int n_in,
                              void* d_out, int out_size, void* d_ws, size_t ws_size,
                              hipStream_t stream) {
  const float4* in4   = (const float4*)d_in[0];
  const float* target = (const float*)d_in[1];
  const float* bias   = (const float*)d_in[2];
  const float* w_fc   = (const float*)d_in[3];
  const float* b_fc   = (const float*)d_in[4];
  float* out = (float*)d_out;
  float* ws  = (float*)d_ws;

  float* partials = ws;
  float* gram     = ws + WS_GRAM_OFF;

  int occ = 0;
  (void)hipOccupancyMaxActiveBlocksPerMultiprocessor(&occ, k_fused, 256, 0);
  if (occ < 1) occ = 1;
  int G = occ * 256;            // 256 CUs on MI355X
  if (G > MAXG) G = MAXG;

  void* args[] = {(void*)&in4, (void*)&target, (void*)&bias, (void*)&w_fc,
                  (void*)&b_fc, (void*)&out, (void*)&partials, (void*)&gram,
                  (void*)&G};
  (void)hipLaunchCooperativeKernel(k_fused, dim3(G), dim3(256), args, 0, stream);
}

// Round 3
// 137.768 us; speedup vs baseline: 5.7208x; 5.7208x over previous
//
#include <hip/hip_runtime.h>
#include <math.h>

#define B_DIM 512
#define C_DIM 8
#define L_DIM 16384

#define NBLK1 2048
#define THREADS1 (NBLK1 * 256)                 // 524288
#define TOTAL_F4 (B_DIM * C_DIM * L_DIM / 4)   // 16777216
#define ITERS1 (TOTAL_F4 / THREADS1)           // 32
#define INV_N (1.0f / (float)(B_DIM * C_DIM * L_DIM))

#define NUNITS (B_DIM * 4)                     // 2048 (batch, quarter) units
#define QLEN (L_DIM / 4)                       // 4096 floats per quarter

// ws layout (floats): [0, 2048) partials ; [2048, 2048 + 2048*44) gram
#define WS_GRAM_OFF 2048

__global__ __launch_bounds__(256) void k_sum(const float4* __restrict__ in,
                                             float* __restrict__ partials) {
  int tid = blockIdx.x * 256 + threadIdx.x;
  float a0 = 0.f, a1 = 0.f, a2 = 0.f, a3 = 0.f;
#pragma unroll
  for (int i = 0; i < ITERS1; i += 4) {
    float4 v0 = in[tid + (i + 0) * THREADS1];
    float4 v1 = in[tid + (i + 1) * THREADS1];
    float4 v2 = in[tid + (i + 2) * THREADS1];
    float4 v3 = in[tid + (i + 3) * THREADS1];
    a0 += (v0.x + v0.y) + (v0.z + v0.w);
    a1 += (v1.x + v1.y) + (v1.z + v1.w);
    a2 += (v2.x + v2.y) + (v2.z + v2.w);
    a3 += (v3.x + v3.y) + (v3.z + v3.w);
  }
  float acc = (a0 + a1) + (a2 + a3);
#pragma unroll
  for (int off = 32; off; off >>= 1) acc += __shfl_down(acc, off, 64);
  __shared__ float s[4];
  int lane = threadIdx.x & 63, wv = threadIdx.x >> 6;
  if (lane == 0) s[wv] = acc;
  __syncthreads();
  if (threadIdx.x == 0) partials[blockIdx.x] = (s[0] + s[1]) + (s[2] + s[3]);
}

// One block per (batch, quarter). 256 threads, 4 float4-iterations per channel.
__global__ __launch_bounds__(256) void k_gram(const float* __restrict__ in,
                                              const float* __restrict__ partials,
                                              const float* __restrict__ bias,
                                              float* __restrict__ gram) {
  const int tid = threadIdx.x;
  const int lane = tid & 63, wv = tid >> 6;
  __shared__ float lds[4 * 44];

  // redundant global-mean reduce: 2048 partials per block (~L2/L3 resident)
  float mu;
  {
    float m = 0.f;
#pragma unroll
    for (int k = 0; k < NBLK1 / 256; ++k) m += partials[tid + k * 256];
#pragma unroll
    for (int off = 32; off; off >>= 1) m += __shfl_down(m, off, 64);
    if (lane == 0) lds[wv] = m;
    __syncthreads();
    mu = ((lds[0] + lds[1]) + (lds[2] + lds[3])) * INV_N;
    __syncthreads();
  }

  const int b = blockIdx.x >> 2, quarter = blockIdx.x & 3;
  const float* base = in + (size_t)b * (C_DIM * L_DIM) + quarter * QLEN;

  float bias_l[C_DIM];
#pragma unroll
  for (int c = 0; c < C_DIM; ++c) bias_l[c] = bias[c];

  // acc[0..7] = per-channel sums; acc[8 + i*(i+1)/2 + j] = inter(i,j), i>=j
  float acc[44];
#pragma unroll
  for (int k = 0; k < 44; ++k) acc[k] = 0.f;

#pragma unroll
  for (int it = 0; it < 4; ++it) {
    const int l4 = (it * 256 + tid) * 4;  // within quarter (0..4095)
    float4 v[C_DIM];
#pragma unroll
    for (int c = 0; c < C_DIM; ++c)
      v[c] = *reinterpret_cast<const float4*>(base + c * L_DIM + l4);
#pragma unroll
    for (int e = 0; e < 4; ++e) {
      float s[C_DIM];
#pragma unroll
      for (int c = 0; c < C_DIM; ++c) {
        float a = (e == 0) ? v[c].x : (e == 1) ? v[c].y : (e == 2) ? v[c].z : v[c].w;
        float arg = fmaf(500.f, a - mu, bias_l[c]);
        float ex = __expf(-arg);
        s[c] = __builtin_amdgcn_rcpf(1.f + ex);
        acc[c] += s[c];
      }
#pragma unroll
      for (int i = 0; i < C_DIM; ++i)
#pragma unroll
        for (int j = 0; j <= i; ++j)
          acc[8 + (i * (i + 1)) / 2 + j] =
              fmaf(s[i], s[j], acc[8 + (i * (i + 1)) / 2 + j]);
    }
  }

  // block-reduce the 44 accumulators
#pragma unroll
  for (int k = 0; k < 44; ++k) {
    float a = acc[k];
#pragma unroll
    for (int off = 32; off; off >>= 1) a += __shfl_down(a, off, 64);
    if (lane == 0) lds[wv * 44 + k] = a;
  }
  __syncthreads();
  if (tid < 44) {
    float r = (lds[0 * 44 + tid] + lds[1 * 44 + tid]) +
              (lds[2 * 44 + tid] + lds[3 * 44 + tid]);
    gram[blockIdx.x * 44 + tid] = r;
  }
}

__global__ __launch_bounds__(512) void k_final(const float* __restrict__ gram,
                                               const float* __restrict__ target,
                                               const float* __restrict__ w_fc,
                                               const float* __restrict__ b_fc,
                                               float* __restrict__ out) {
  const int b = threadIdx.x;  // 512 threads, one per batch
  float S[C_DIM], T[36];
#pragma unroll
  for (int k = 0; k < C_DIM; ++k) {
    float v = 0.f;
#pragma unroll
    for (int q = 0; q < 4; ++q) v += gram[(b * 4 + q) * 44 + k];
    S[k] = v;
  }
#pragma unroll
  for (int k = 0; k < 36; ++k) {
    float v = 0.f;
#pragma unroll
    for (int q = 0; q < 4; ++q) v += gram[(b * 4 + q) * 44 + 8 + k];
    T[k] = v;
  }

  float st = 0.f;
#pragma unroll
  for (int i = 0; i < C_DIM; ++i)
#pragma unroll
    for (int j = 0; j <= i; ++j) {
      float inter = T[(i * (i + 1)) / 2 + j];
      float uni = (S[i] + S[j]) - inter;
      float sim = inter / uni;
      float tm = 100.f * target[b * 64 + i * 8 + j];
      st += fabsf(sim - tm);
    }

  __shared__ float rs[512];
  rs[b] = st;
  __syncthreads();
  for (int off = 256; off; off >>= 1) {
    if (b < off) rs[b] += rs[b + off];
    __syncthreads();
  }
  const float mean = rs[0] * (1.f / 512.f);
  __syncthreads();
  float d = st - mean;
  rs[b] = d * d;
  __syncthreads();
  for (int off = 256; off; off >>= 1) {
    if (b < off) rs[b] += rs[b + off];
    __syncthreads();
  }
  const float var = rs[0] * (1.f / 512.f);
  const float stn = (st - mean) * rsqrtf(var + 1e-5f);
#pragma unroll
  for (int k = 0; k < 3; ++k)
    out[b * 3 + k] = fmaf(stn, w_fc[k], b_fc[k]);
}

extern "C" void kernel_launch(void* const* d_in, const int* in_sizes, int n_in,
                              void* d_out, int out_size, void* d_ws, size_t ws_size,
                              hipStream_t stream) {
  const float* attn   = (const float*)d_in[0];
  const float* target = (const float*)d_in[1];
  const float* bias   = (const float*)d_in[2];
  const float* w_fc   = (const float*)d_in[3];
  const float* b_fc   = (const float*)d_in[4];
  float* out = (float*)d_out;
  float* ws  = (float*)d_ws;

  float* partials = ws;
  float* gram     = ws + WS_GRAM_OFF;

  k_sum<<<NBLK1, 256, 0, stream>>>((const float4*)attn, partials);
  k_gram<<<NUNITS, 256, 0, stream>>>(attn, partials, bias, gram);
  k_final<<<1, 512, 0, stream>>>(gram, target, w_fc, b_fc, out);
}